// Round 5
// baseline (188.666 us; speedup 1.0000x reference)
//
#include <hip/hip_runtime.h>
#include <hip/hip_bf16.h>
#include <math.h>

// Problem constants (from reference setup_inputs)
constexpr int B_  = 192;
constexpr int NY  = 48;
constexpr int NT  = 48;
constexpr int C_  = 6625;

// DIAGNOSTIC ROUND: NPASS-1 extra cold gather passes at shifted columns make
// this kernel the top-duration dispatch so rocprof finally shows the gather's
// FETCH_SIZE / hbm_gbps (the harness's 140us fills otherwise hide it).
// The real pipeline (pass 0) is bit-identical to R1 (passed, absmax 0.0).
constexpr int NPASS = 12;

__global__ __launch_bounds__(256) void ep_forward_kernel(
    const float* __restrict__ pred,
    const float* __restrict__ R,
    const float* __restrict__ I,
    const int*   __restrict__ tgt,
    float* __restrict__ out_logs,
    float* __restrict__ dummy)
{
    __shared__ float sP[NT][NY];
    __shared__ float sI[NT][NY];
    __shared__ int   sT[NT];

    const int b   = blockIdx.x;
    const int tid = threadIdx.x;

    if (tid < NT) sT[tid] = tgt[b * NT + tid];
    __syncthreads();

    const float* predB = pred + (size_t)b * NY * C_;
    const float* IB    = I    + (size_t)b * NY * C_;

    // ---- real gather (identical to R1) ----
    #pragma unroll
    for (int k = 0; k < 9; ++k) {
        int e = tid + k * 256;           // e in [0, 2304)
        int t = e / NY;
        int j = e - t * NY;
        int c = sT[t];
        size_t off = (size_t)j * C_ + (size_t)c;
        sP[t][j] = fmaxf(predB[off], 0.0f);
        sI[t][j] = fmaxf(IB[off],    0.0f);
    }
    __syncthreads();

    // ---- cold probe passes: same pattern, distinct lines each pass ----
    float acc = 0.0f;
    for (int p = 1; p < NPASS; ++p) {
        #pragma unroll
        for (int k = 0; k < 9; ++k) {
            int e = tid + k * 256;
            int t = e / NY;
            int j = e - t * NY;
            int cc = (sT[t] + p * 811) % C_;
            size_t off = (size_t)j * C_ + (size_t)cc;
            acc += predB[off] + IB[off];
        }
    }
    dummy[b * 256 + tid] = acc;          // keep probes live; deterministic

    // ---- Phase 2: recurrence (wave 0, lanes 0..47 only), identical to R1 ----
    if (tid >= NY) return;
    const int j = tid;

    const float* Rb = R + ((size_t)b * NY + j) * 3;
    float R0 = Rb[0];
    float R1 = Rb[1];
    float R2 = Rb[2];
    float Imult  = (j == NY - 1) ? 1.0f : R1;
    float R2prev = __shfl_up(R2, 1);

    {
        float d0 = (sT[0] == 1) ? 1.0f : R2;
        float v  = (j == 0) ? 1.0f : d0;
        #pragma unroll
        for (int s = 1; s < 64; s <<= 1) {
            float p = __shfl_up(v, s);
            if (j >= s) v *= p;
        }
        float row = v;

        for (int t = 0; t < NT - 1; ++t) {
            float pg = sP[t][j];
            float ig = sI[t][j];
            float pC = R0 * pg;
            float pI = Imult * ig;

            float u  = row * pC;
            float up = __shfl_up(u, 1);
            float a  = row * pI + ((j >= 1) ? up : 0.0f);

            bool is1 = (sT[t + 1] == 1);
            float m = (j == 0) ? 0.0f : (is1 ? 1.0f : R2prev);
            float c = a;
            #pragma unroll
            for (int s = 1; s < 64; s <<= 1) {
                float cp = __shfl_up(c, s);
                float mp = __shfl_up(m, s);
                if (j >= s) {
                    c = fmaf(m, cp, c);
                    m = m * mp;
                }
            }
            row = c;
        }

        if (j == NY - 1) out_logs[b] = logf(row);
    }
}

// Kernel 2: deterministic reduction of 192 per-batch logs -> mean
__global__ __launch_bounds__(256) void ep_reduce_kernel(
    const float* __restrict__ logs, float* __restrict__ out)
{
    const int tid = threadIdx.x;
    float v = (tid < B_) ? logs[tid] : 0.0f;
    #pragma unroll
    for (int s = 1; s < 64; s <<= 1) v += __shfl_xor(v, s);
    __shared__ float sw[4];
    if ((tid & 63) == 0) sw[tid >> 6] = v;
    __syncthreads();
    if (tid == 0) out[0] = (sw[0] + sw[1] + sw[2] + sw[3]) * (1.0f / (float)B_);
}

extern "C" void kernel_launch(void* const* d_in, const int* in_sizes, int n_in,
                              void* d_out, int out_size, void* d_ws, size_t ws_size,
                              hipStream_t stream) {
    const float* pred = (const float*)d_in[0];
    const float* R    = (const float*)d_in[1];
    const float* I    = (const float*)d_in[2];
    const int*   tgt  = (const int*)d_in[3];
    float* out   = (float*)d_out;
    float* logs  = (float*)d_ws;                       // 192 floats
    float* dummy = (float*)((char*)d_ws + 4096);       // 192*256 floats (probe sink)

    ep_forward_kernel<<<B_, 256, 0, stream>>>(pred, R, I, tgt, logs, dummy);
    ep_reduce_kernel<<<1, 256, 0, stream>>>(logs, out);
}

// Round 6
// 38.605 us; speedup vs baseline: 4.8871x; 4.8871x over previous
//
#include <hip/hip_runtime.h>
#include <hip/hip_bf16.h>
#include <math.h>

// Problem constants (from reference setup_inputs)
constexpr int B_  = 192;
constexpr int NY  = 48;
constexpr int NT  = 48;
constexpr int C_  = 6625;

// DPP move helper (compile-time ctrl). Invalid/masked lanes get `identity`.
template<int CTRL, int RM>
__device__ __forceinline__ float dpp_movf(float identity, float x) {
    int r = __builtin_amdgcn_update_dpp(__builtin_bit_cast(int, identity),
                                        __builtin_bit_cast(int, x),
                                        CTRL, RM, 0xf, false);
    return __builtin_bit_cast(float, r);
}
// ctrl: ROW_SHR|n = 0x110|n, WAVE_SHR1 = 0x138, ROW_BCAST15 = 0x142, ROW_BCAST31 = 0x143

// Fused kernel: R1's gather (measured at the 2.67 TB/s random-line ceiling)
// + DPP affine scan (validated bit-exact in R2/R3) + last-block reduction
// (validated in R2). One launch total.
__global__ __launch_bounds__(256) void ep_fused_kernel(
    const float* __restrict__ pred,
    const float* __restrict__ R,
    const float* __restrict__ I,
    const int*   __restrict__ tgt,
    float* __restrict__ logs,
    int*   __restrict__ cnt,
    float* __restrict__ out)
{
    __shared__ float sP[NT][NY];
    __shared__ float sI[NT][NY];
    __shared__ int   sT[NT];
    __shared__ int   sLast;
    __shared__ float sRed[3];

    const int b   = blockIdx.x;
    const int tid = threadIdx.x;

    if (tid == 0) sLast = 0;
    if (tid < NT) sT[tid] = tgt[b * NT + tid];

    // Hoist R loads so they overlap the gather (used only after the barrier).
    float R0 = 0.0f, R1v = 0.0f, R2v = 0.0f;
    if (tid < NY) {
        const float* Rb = R + ((size_t)b * NY + tid) * 3;
        R0  = Rb[0];
        R1v = Rb[1];
        R2v = Rb[2];
    }
    __syncthreads();

    // ---- Phase 1: gather (identical to R1's best-measured pattern) ----
    const float* predB = pred + (size_t)b * NY * C_;
    const float* IB    = I    + (size_t)b * NY * C_;
    #pragma unroll
    for (int k = 0; k < 9; ++k) {
        int e = tid + k * 256;           // e in [0, 2304)
        int t = e / NY;
        int j = e - t * NY;
        int c = sT[t];
        size_t off = (size_t)j * C_ + (size_t)c;
        sP[t][j] = fmaxf(predB[off], 0.0f);
        sI[t][j] = fmaxf(IB[off],    0.0f);
    }
    __syncthreads();

    // ---- Phase 2: DPP affine-scan recurrence (wave 0, lanes 0..47) ----
    if (tid < NY) {
        const int j = tid;
        float Imult  = (j == NY - 1) ? 1.0f : R1v;
        float R2prev = dpp_movf<0x138, 0xf>(0.0f, R2v);   // R2[j-1]

        // row0: multiplicative scan of d0 = (tgt[0]==1) ? 1 : R2
        float d0 = (sT[0] == 1) ? 1.0f : R2v;
        float v  = (j == 0) ? 1.0f : d0;
        v *= dpp_movf<0x111, 0xf>(1.0f, v);
        v *= dpp_movf<0x112, 0xf>(1.0f, v);
        v *= dpp_movf<0x114, 0xf>(1.0f, v);
        v *= dpp_movf<0x118, 0xf>(1.0f, v);
        v *= dpp_movf<0x142, 0xa>(1.0f, v);
        v *= dpp_movf<0x143, 0xc>(1.0f, v);
        float row = v;

        float pg = sP[0][j];
        float ig = sI[0][j];
        for (int t = 0; t < NT - 1; ++t) {
            float pgn = sP[t + 1][j];     // prefetch next iteration
            float ign = sI[t + 1][j];

            // a[j] = row[j]*pI[j] + row[j-1]*pC[j-1]
            float u  = row * (R0 * pg);
            float up = dpp_movf<0x138, 0xf>(0.0f, u);
            float c  = fmaf(row, Imult * ig, up);
            // scan multiplier m = d[j-1] (lane 0: 0)
            float m  = (j == 0) ? 0.0f : ((sT[t + 1] == 1) ? 1.0f : R2prev);

            // inclusive affine-map scan (validated DPP pattern)
            { float mp = dpp_movf<0x111, 0xf>(1.0f, m), cp = dpp_movf<0x111, 0xf>(0.0f, c); c = fmaf(m, cp, c); m *= mp; }
            { float mp = dpp_movf<0x112, 0xf>(1.0f, m), cp = dpp_movf<0x112, 0xf>(0.0f, c); c = fmaf(m, cp, c); m *= mp; }
            { float mp = dpp_movf<0x114, 0xf>(1.0f, m), cp = dpp_movf<0x114, 0xf>(0.0f, c); c = fmaf(m, cp, c); m *= mp; }
            { float mp = dpp_movf<0x118, 0xf>(1.0f, m), cp = dpp_movf<0x118, 0xf>(0.0f, c); c = fmaf(m, cp, c); m *= mp; }
            { float mp = dpp_movf<0x142, 0xa>(1.0f, m), cp = dpp_movf<0x142, 0xa>(0.0f, c); c = fmaf(m, cp, c); m *= mp; }
            { float mp = dpp_movf<0x143, 0xc>(1.0f, m), cp = dpp_movf<0x143, 0xc>(0.0f, c); c = fmaf(m, cp, c); m *= mp; }
            row = c;

            pg = pgn; ig = ign;
        }

        if (j == NY - 1) {
            logs[b] = logf(row);
            __threadfence();              // release this block's log
            int old = __hip_atomic_fetch_add(cnt, 1, __ATOMIC_ACQ_REL,
                                             __HIP_MEMORY_SCOPE_AGENT);
            if (old == B_ - 1) sLast = 1;
        }
    }
    __syncthreads();

    // ---- Last-finishing block: deterministic fixed-order mean of 192 logs ----
    if (sLast) {
        float x = 0.0f;
        if (tid < B_)
            x = __hip_atomic_load(&logs[tid], __ATOMIC_RELAXED,
                                  __HIP_MEMORY_SCOPE_AGENT);
        #pragma unroll
        for (int s = 1; s < 64; s <<= 1) x += __shfl_xor(x, s);
        if ((tid & 63) == 0 && tid < B_) sRed[tid >> 6] = x;
        __syncthreads();
        if (tid == 0) out[0] = (sRed[0] + sRed[1] + sRed[2]) * (1.0f / (float)B_);
    }
}

extern "C" void kernel_launch(void* const* d_in, const int* in_sizes, int n_in,
                              void* d_out, int out_size, void* d_ws, size_t ws_size,
                              hipStream_t stream) {
    const float* pred = (const float*)d_in[0];
    const float* R    = (const float*)d_in[1];
    const float* I    = (const float*)d_in[2];
    const int*   tgt  = (const int*)d_in[3];
    float* out  = (float*)d_out;
    float* logs = (float*)d_ws;                      // 192 floats
    int*   cnt  = (int*)((char*)d_ws + 768);         // completion counter

    hipMemsetAsync(cnt, 0, sizeof(int), stream);     // graph-capturable node
    ep_fused_kernel<<<B_, 256, 0, stream>>>(pred, R, I, tgt, logs, cnt, out);
}